// Round 6
// baseline (760.112 us; speedup 1.0000x reference)
//
#include <hip/hip_runtime.h>
#include <stdint.h>
#include <math.h>

// Problem constants (B=2,S=2048,H=1024,E=8,K=2,F=4096)
#define T_TOK 4096
#define H_DIM 1024
#define E_EXP 8
#define F_DIM 4096
#define NASSIGN (T_TOK * 2)
#define OUT_ELEMS ((size_t)T_TOK * H_DIM)
#define YB_ELEMS ((size_t)8192 * H_DIM)   // one split-K slab: [8192][H] f32

typedef unsigned short u16;
typedef __attribute__((ext_vector_type(8))) short short8;   // 8 bf16 = 4 VGPRs
typedef __attribute__((ext_vector_type(4))) short short4v;  // 4 bf16 = 2 VGPRs
typedef __attribute__((ext_vector_type(4))) float f32x4;

__device__ __forceinline__ u16 f2bf(float f) {
  union { float f; uint32_t u; } c; c.f = f;
  uint32_t u = c.u;
  return (u16)((u + 0x7FFFu + ((u >> 16) & 1u)) >> 16);  // RNE
}

// fast erf (Abramowitz-Stegun 7.1.26, |abs err| <= 1.5e-7)
__device__ __forceinline__ float fast_erf(float u) {
  const float au = fabsf(u);
  const float t = __builtin_amdgcn_rcpf(__builtin_fmaf(0.3275911f, au, 1.0f));
  float p = __builtin_fmaf(1.061405429f, t, -1.453152027f);
  p = __builtin_fmaf(p, t, 1.421413741f);
  p = __builtin_fmaf(p, t, -0.284496736f);
  p = __builtin_fmaf(p, t, 0.254829592f);
  p = p * t;
  const float y = __builtin_fmaf(-p, __expf(-au * au), 1.0f);
  return copysignf(y, u);
}

// async global->LDS, 16B per lane. LDS dest is wave-uniform base + lane*16.
__device__ __forceinline__ void gl_lds16(const void* g, void* l) {
  __builtin_amdgcn_global_load_lds(
      (const __attribute__((address_space(1))) uint32_t*)g,
      (__attribute__((address_space(3))) uint32_t*)(uintptr_t)l, 16, 0, 0);
}

// raw workgroup barrier: NO implicit vmcnt drain (unlike __syncthreads).
__device__ __forceinline__ void wg_barrier() {
  asm volatile("" ::: "memory");
  __builtin_amdgcn_s_barrier();
  asm volatile("" ::: "memory");
}

// ---------------- fused prep: router + W1 transpose + W2 transpose ----------------
// in: [E][R][C] fp32 (R = K-dim, C = N-dim)
// out: [E][C/64][R/64][64][64] bf16, inner tile [c-local][r-local], r contiguous.
// Pad 73 (not 72): with 72, phase-2 reads stride 8 rows x 144B == 0 mod 128 ->
// 8-way bank conflict; 146B stride gives bank offset 4/row-group -> conflict-free.
__device__ __forceinline__ void transpose_tile(
    const float* __restrict__ in, u16* __restrict__ out, int R, int C,
    int bx, int by, int bz, u16 (*tile)[73]) {
  const size_t eoff = (size_t)bz * R * C;
  {
    const int c4 = (threadIdx.x & 15) * 4;
    const int rr = threadIdx.x >> 4;
    const float* inp = in + eoff + ((size_t)by * 64) * C + bx * 64;
#pragma unroll
    for (int p = 0; p < 4; ++p) {
      const int r = rr + p * 16;
      const float4 v = *(const float4*)(inp + (size_t)r * C + c4);
      tile[r][c4 + 0] = f2bf(v.x); tile[r][c4 + 1] = f2bf(v.y);
      tile[r][c4 + 2] = f2bf(v.z); tile[r][c4 + 3] = f2bf(v.w);
    }
  }
  __syncthreads();
  {
    u16* op = out + (((size_t)bz * (C >> 6) + bx) * (R >> 6) + by) * 4096;
#pragma unroll
    for (int p = 0; p < 2; ++p) {
      const int c = (threadIdx.x >> 3) + p * 32;
      const int rg = (threadIdx.x & 7) * 8;
      short8 o;
#pragma unroll
      for (int j = 0; j < 8; ++j) o[j] = (short)tile[rg + j][c];
      *(short8*)(op + c * 64 + rg) = o;
    }
  }
}

__global__ __launch_bounds__(256) void prep_kernel(
    const float* __restrict__ x, const float* __restrict__ Wr,
    const float* __restrict__ br, u16* __restrict__ xb,
    int* __restrict__ tki, float* __restrict__ tkw,
    int* __restrict__ counts, float* __restrict__ zsum,
    const float* __restrict__ W1, u16* __restrict__ w1t,
    const float* __restrict__ W2, u16* __restrict__ w2t) {
  __shared__ u16 tile[64][73];
  __shared__ int lcnt[8];
  __shared__ float lzv[16];
  const int id = blockIdx.x;

  if (id >= 256) {
    if (id < 8448) {
      const int q = id - 256;   // W1 [E][H][F]: R=H(K), C=F(N)
      transpose_tile(W1, w1t, H_DIM, F_DIM, q & 63, (q >> 6) & 15, q >> 10, tile);
    } else {
      const int q = id - 8448;  // W2 [E][F][H]: R=F(K), C=H(N)
      transpose_tile(W2, w2t, F_DIM, H_DIM, q & 15, (q >> 4) & 63, q >> 10, tile);
    }
    return;
  }

  // ---- router: 16 tokens per block (4 waves x 4 tokens), float4 x loads ----
  const int wave = threadIdx.x >> 6;
  const int lane = threadIdx.x & 63;
  if (threadIdx.x < 8) lcnt[threadIdx.x] = 0;
  __syncthreads();
#pragma unroll
  for (int it = 0; it < 4; ++it) {
    const int t = id * 16 + wave * 4 + it;
    const float* xr = x + (size_t)t * H_DIM;
    u16* xbr = xb + (size_t)t * H_DIM;
    float acc[8];
#pragma unroll
    for (int e = 0; e < 8; ++e) acc[e] = 0.0f;
#pragma unroll
    for (int j = 0; j < 4; ++j) {
      const int h0 = j * 256 + lane * 4;
      const float4 xv = *(const float4*)(xr + h0);
      const float vv[4] = {xv.x, xv.y, xv.z, xv.w};
      short4v pk;
#pragma unroll
      for (int i = 0; i < 4; ++i) {
        pk[i] = (short)f2bf(vv[i]);
        const float4 w0 = *(const float4*)(Wr + (size_t)(h0 + i) * 8);
        const float4 w1 = *(const float4*)(Wr + (size_t)(h0 + i) * 8 + 4);
        acc[0] += vv[i] * w0.x; acc[1] += vv[i] * w0.y;
        acc[2] += vv[i] * w0.z; acc[3] += vv[i] * w0.w;
        acc[4] += vv[i] * w1.x; acc[5] += vv[i] * w1.y;
        acc[6] += vv[i] * w1.z; acc[7] += vv[i] * w1.w;
      }
      *(short4v*)(xbr + h0) = pk;
    }
#pragma unroll
    for (int e = 0; e < 8; ++e) {
      float v = acc[e];
#pragma unroll
      for (int s = 32; s > 0; s >>= 1) v += __shfl_xor(v, s);
      acc[e] = v;
    }
    if (lane == 0) {
      float l[8];
#pragma unroll
      for (int e = 0; e < 8; ++e) l[e] = acc[e] + br[e];
      float mx = l[0];
#pragma unroll
      for (int e = 1; e < 8; ++e) mx = fmaxf(mx, l[e]);
      float p[8], s = 0.0f;
#pragma unroll
      for (int e = 0; e < 8; ++e) { p[e] = __expf(l[e] - mx); s += p[e]; }
      int i0 = 0;
#pragma unroll
      for (int e = 1; e < 8; ++e) if (p[e] > p[i0]) i0 = e;
      int i1 = (i0 == 0) ? 1 : 0;
#pragma unroll
      for (int e = 0; e < 8; ++e) if (e != i1 && e != i0 && p[e] > p[i1]) i1 = e;
      const float ws = p[i0] + p[i1];
      tki[2 * t] = i0; tki[2 * t + 1] = i1;
      tkw[2 * t] = p[i0] / ws; tkw[2 * t + 1] = p[i1] / ws;
      atomicAdd(&lcnt[i0], 1);
      atomicAdd(&lcnt[i1], 1);
      lzv[wave * 4 + it] = mx + logf(s);
    }
  }
  __syncthreads();
  if (threadIdx.x < 8) {
    const int c = lcnt[threadIdx.x];
    if (c) atomicAdd(&counts[threadIdx.x], c);
  }
  if (threadIdx.x == 64) {
    float zs = 0.0f;
#pragma unroll
    for (int i = 0; i < 16; ++i) zs += lzv[i];
    atomicAdd(zsum, zs);
  }
}

// scatter + (block 0) loss. Per-wave ballot aggregation for cursor atomics.
__global__ void scatter_kernel(const int* __restrict__ tki, const float* __restrict__ tkw,
                               const int* __restrict__ counts, int* __restrict__ cursor,
                               int* __restrict__ perm, float* __restrict__ pw,
                               int* __restrict__ islot,
                               const float* __restrict__ zsum, float* __restrict__ out_loss) {
  int offs[8];
  {
    int a = 0;
#pragma unroll
    for (int e = 0; e < 8; ++e) { offs[e] = a; a += counts[e]; }
  }
  const int lane = threadIdx.x & 63;
  const int t = blockIdx.x * 256 + threadIdx.x;
#pragma unroll
  for (int k = 0; k < 2; ++k) {
    const int e = tki[2 * t + k];
    int slot = 0;
#pragma unroll
    for (int ee = 0; ee < 8; ++ee) {
      const unsigned long long mask = __ballot(e == ee);
      if (mask) {
        const int leader = __ffsll(mask) - 1;
        int b = 0;
        if (lane == leader) b = atomicAdd(&cursor[ee], (int)__popcll(mask));
        b = __shfl(b, leader);
        if (e == ee) {
          const int r = (int)__popcll(mask & ((1ull << lane) - 1ull));
          slot = offs[ee] + b + r;
        }
      }
    }
    perm[slot] = t;
    pw[slot] = tkw[2 * t + k];
    islot[2 * t + k] = slot;
  }
  if (blockIdx.x == 0 && threadIdx.x == 0) {
    float aux = 0.0f;
#pragma unroll
    for (int e = 0; e < 8; ++e) {
      const float d = (float)counts[e] / (float)NASSIGN - 0.125f;
      aux += d * d;
    }
    aux *= (1.0f / 8.0f);
    out_loss[0] = 0.01f * aux + 0.001f * (zsum[0] / (float)T_TOK);
  }
}

// ---------------- grouped GEMMs: 256x256 tile, 4 waves, wave tile 128x128 ----------------
// LDS-BW model: per wave-K-step(64) reads = 16 b128 feed 128 MFMAs (2x fewer
// LDS bytes/FLOP than the old 4x4 wave). acc[8][8] f32x4 -> AGPRs; 1 wave/SIMD.
// Double-buffered 128KB LDS + counted vmcnt(16): next tile's 16 gl_lds stay in
// flight across the raw barrier (r4 skeleton, correctness-verified).
// id&7 = expert -> XCD affinity.

#define STAGE16(BUFOFF)                                                  \
  {                                                                      \
    const int nb_ = (BUFOFF);                                            \
    _Pragma("unroll")                                                    \
    for (int l = 0; l < 8; ++l) {                                        \
      gl_lds16(ap[l], &smem[nb_ + l * 2048 + tid * 8]);          ap[l] += 64; \
      gl_lds16(bp[l], &smem[nb_ + 16384 + l * 2048 + tid * 8]);  bp[l] += 4096; \
    }                                                                    \
  }

#define COMPUTE256(BUFOFF)                                               \
  {                                                                      \
    const short8* Af = (const short8*)(smem + (BUFOFF));                 \
    const short8* Bf = Af + 2048;                                        \
    _Pragma("unroll")                                                    \
    for (int s = 0; s < 2; ++s) {                                        \
      const int qs = s ? qs1 : qs0;                                      \
      short8 a[8];                                                       \
      _Pragma("unroll")                                                  \
      for (int i = 0; i < 8; ++i) a[i] = Af[(wm + i * 16 + lr) * 8 + qs]; \
      _Pragma("unroll")                                                  \
      for (int j = 0; j < 8; ++j) {                                      \
        const short8 b = Bf[(wn + j * 16 + lr) * 8 + qs];                \
        _Pragma("unroll")                                                \
        for (int i = 0; i < 8; ++i)                                      \
          acc[i][j] = __builtin_amdgcn_mfma_f32_16x16x32_bf16(a[i], b, acc[i][j], 0, 0, 0); \
      }                                                                  \
    }                                                                    \
  }

// h[slot][F] = gelu( xb[perm[slot]] @ W1t[e]^T + b1[e] )  (bf16 out)
__global__ __launch_bounds__(256, 1) void gemm1_kernel(
    const u16* __restrict__ xb, const u16* __restrict__ w1t,
    const float* __restrict__ b1, const int* __restrict__ perm,
    const int* __restrict__ cnts, u16* __restrict__ hbuf) {
  const int id = blockIdx.x;
  const int e = id & 7;
  const int wq = id >> 3;
  const int n0 = (wq & 15) << 8;      // 16 n-blocks of 256
  const int m0 = (wq >> 4) << 8;      // 16 m-slots of 256
  int cnt, off;
  {
    int a = 0, c = 0;
#pragma unroll
    for (int i = 0; i < 8; ++i) { const int ci = cnts[i]; if (i < e) a += ci; if (i == e) c = ci; }
    cnt = c; off = a;
  }
  if (m0 >= cnt) return;

  // 2 dbuf x (A[256][64] + B[256][64]) bf16 = 128KB; epilogue reuses as [256][256] bf16
  __shared__ __align__(16) u16 smem[65536];

  const int tid = threadIdx.x;
  const int rbase = tid >> 3;                    // 0..31
  const int kc = ((tid & 7) ^ (rbase & 7)) * 8;  // swizzled source chunk

  const u16* ap[8];
#pragma unroll
  for (int l = 0; l < 8; ++l) {
    int ra = m0 + rbase + l * 32; if (ra > cnt - 1) ra = cnt - 1;
    ap[l] = xb + (size_t)perm[off + ra] * H_DIM + kc;
  }
  const u16* bp[8];
#pragma unroll
  for (int l = 0; l < 8; ++l)
    bp[l] = w1t + (((size_t)e * (F_DIM >> 6) + (n0 >> 6) + (l >> 1)) * (H_DIM >> 6)) * 4096
          + ((l & 1) * 32 + rbase) * 64 + kc;

  const int wave = tid >> 6, lane = tid & 63;
  const int wm = (wave >> 1) * 128, wn = (wave & 1) * 128;
  const int lr = lane & 15, q = lane >> 4;
  const int qs0 = q ^ (lr & 7), qs1 = (4 + q) ^ (lr & 7);

  f32x4 acc[8][8];
#pragma unroll
  for (int i = 0; i < 8; ++i)
#pragma unroll
    for (int j = 0; j < 8; ++j) acc[i][j] = (f32x4)0.0f;

  int cur = 0;
  STAGE16(0);                          // tile 0 -> buf 0
  for (int k0 = 0; k0 < (H_DIM >> 6) - 1; ++k0) {
    STAGE16((cur ^ 1) << 15);          // next tile: 16 loads stay in flight
    asm volatile("s_waitcnt vmcnt(16)" ::: "memory");   // current tile landed
    __builtin_amdgcn_sched_barrier(0);
    wg_barrier();
    COMPUTE256(cur << 15);
    wg_barrier();
    cur ^= 1;
  }
  asm volatile("s_waitcnt vmcnt(0)" ::: "memory");
  __builtin_amdgcn_sched_barrier(0);
  wg_barrier();
  COMPUTE256(cur << 15);
  wg_barrier();                        // LDS about to be repurposed

  // Epilogue: bias+gelu -> bf16 -> LDS [256][256] (XOR col swizzle) -> 16B stores.
#pragma unroll
  for (int i = 0; i < 8; ++i) {
#pragma unroll
    for (int rr = 0; rr < 4; ++rr) {
      const int row = wm + i * 16 + q * 4 + rr;
#pragma unroll
      for (int j = 0; j < 8; ++j) {
        const int col = wn + j * 16 + lr;
        const float v = acc[i][j][rr] + b1[e * F_DIM + n0 + col];
        const float g = 0.5f * v * (1.0f + fast_erf(v * 0.70710678118654752f));
        smem[(row << 8) + (col ^ (q << 4))] = f2bf(g);
      }
    }
  }
  __syncthreads();
#pragma unroll
  for (int p = 0; p < 32; ++p) {
    const int row = p * 8 + (tid >> 5);
    const int c8 = (tid & 31) * 8;
    const int m = m0 + row;
    if (m < cnt) {
      const int qq = (row >> 2) & 3;
      *(short8*)(hbuf + (size_t)(off + m) * F_DIM + n0 + c8) =
          *(const short8*)(smem + (row << 8) + (c8 ^ (qq << 4)));
    }
  }
}

// ybuf[ks][slot] = w_slot * (h[slot] @ W2t[e]^T [k-half ks] + (ks==0)*b2[e])
__global__ __launch_bounds__(256, 1) void gemm2_kernel(
    const u16* __restrict__ hbuf, const u16* __restrict__ w2t,
    const float* __restrict__ b2, const float* __restrict__ pw,
    const int* __restrict__ cnts, float* __restrict__ ybuf) {
  const int id = blockIdx.x;
  const int e = id & 7;
  const int wq = id >> 3;
  const int n0 = (wq & 3) << 8;       // 4 n-blocks of 256
  const int ks = (wq >> 2) & 1;       // 2 K-splits (2048 each)
  const int m0 = (wq >> 3) << 8;      // 16 m-slots
  int cnt, off;
  {
    int a = 0, c = 0;
#pragma unroll
    for (int i = 0; i < 8; ++i) { const int ci = cnts[i]; if (i < e) a += ci; if (i == e) c = ci; }
    cnt = c; off = a;
  }
  if (m0 >= cnt) return;

  __shared__ __align__(16) u16 smem[65536];

  const int tid = threadIdx.x;
  const int rbase = tid >> 3;
  const int kc = ((tid & 7) ^ (rbase & 7)) * 8;

  const u16* ap[8];
#pragma unroll
  for (int l = 0; l < 8; ++l) {
    int ra = m0 + rbase + l * 32; if (ra > cnt - 1) ra = cnt - 1;
    ap[l] = hbuf + (size_t)(off + ra) * F_DIM + (ks << 11) + kc;
  }
  const u16* bp[8];
#pragma unroll
  for (int l = 0; l < 8; ++l)
    bp[l] = w2t + (((size_t)e * (H_DIM >> 6) + (n0 >> 6) + (l >> 1)) * (F_DIM >> 6)
                   + (ks << 5)) * 4096 + ((l & 1) * 32 + rbase) * 64 + kc;

  const int wave = tid >> 6, lane = tid & 63;
  const int wm = (wave >> 1) * 128, wn = (wave & 1) * 128;
  const int lr = lane & 15, q = lane >> 4;
  const int qs0 = q ^ (lr & 7), qs1 = (4 + q) ^ (lr & 7);

  f32x4 acc[8][8];
#pragma unroll
  for (int i = 0; i < 8; ++i)
#pragma unroll
    for (int j = 0; j < 8; ++j) acc[i][j] = (f32x4)0.0f;

  int cur = 0;
  STAGE16(0);
  for (int k0 = 0; k0 < 31; ++k0) {   // 2048/64 - 1
    STAGE16((cur ^ 1) << 15);
    asm volatile("s_waitcnt vmcnt(16)" ::: "memory");
    __builtin_amdgcn_sched_barrier(0);
    wg_barrier();
    COMPUTE256(cur << 15);
    wg_barrier();
    cur ^= 1;
  }
  asm volatile("s_waitcnt vmcnt(0)" ::: "memory");
  __builtin_amdgcn_sched_barrier(0);
  wg_barrier();
  COMPUTE256(cur << 15);

  // Epilogue: per-slot weighted partial, plain f32 stores into slab ks.
  float* yb = ybuf + (size_t)ks * YB_ELEMS;
#pragma unroll
  for (int i = 0; i < 8; ++i) {
#pragma unroll
    for (int rr = 0; rr < 4; ++rr) {
      const int m = m0 + wm + i * 16 + q * 4 + rr;
      if (m < cnt) {
        const int slot = off + m;
        const float w = pw[slot];
        float* orow = yb + (size_t)slot * H_DIM;
#pragma unroll
        for (int j = 0; j < 8; ++j) {
          const int col = n0 + wn + j * 16 + lr;
          float y = acc[i][j][rr];
          if (ks == 0) y += b2[e * H_DIM + col];
          orow[col] = w * y;
        }
      }
    }
  }
}

// out[t] = sum over k of (ybuf0[slot_k] + ybuf1[slot_k])
__global__ __launch_bounds__(256) void combine_kernel(
    const float* __restrict__ ybuf, const int* __restrict__ islot,
    float* __restrict__ out) {
  const int t = blockIdx.x;
  const int s0 = islot[2 * t];
  const int s1 = islot[2 * t + 1];
  const int c = threadIdx.x * 4;
  const float4 a0 = *(const float4*)(ybuf + (size_t)s0 * H_DIM + c);
  const float4 a1 = *(const float4*)(ybuf + YB_ELEMS + (size_t)s0 * H_DIM + c);
  const float4 b0 = *(const float4*)(ybuf + (size_t)s1 * H_DIM + c);
  const float4 b1 = *(const float4*)(ybuf + YB_ELEMS + (size_t)s1 * H_DIM + c);
  float4 r;
  r.x = a0.x + a1.x + b0.x + b1.x;
  r.y = a0.y + a1.y + b0.y + b1.y;
  r.z = a0.z + a1.z + b0.z + b1.z;
  r.w = a0.w + a1.w + b0.w + b1.w;
  *(float4*)(out + (size_t)t * H_DIM + c) = r;
}

// ---------------- launch ----------------

extern "C" void kernel_launch(void* const* d_in, const int* in_sizes, int n_in,
                              void* d_out, int out_size, void* d_ws, size_t ws_size,
                              hipStream_t stream) {
  const float* x  = (const float*)d_in[0];
  const float* Wr = (const float*)d_in[1];
  const float* br = (const float*)d_in[2];
  const float* W1 = (const float*)d_in[3];
  const float* b1 = (const float*)d_in[4];
  const float* W2 = (const float*)d_in[5];
  const float* b2 = (const float*)d_in[6];
  float* out = (float*)d_out;

  // workspace layout (~210 MB)
  char* ws = (char*)d_ws;
  u16* xb    = (u16*)(ws);                          // 8 MB
  u16* w1t   = (u16*)(ws + 8388608ull);             // 64 MB  tiled [E][F/64][H/64][64][64]
  u16* w2t   = (u16*)(ws + 75497472ull);            // 64 MB  tiled [E][H/64][F/64][64][64]
  u16* hbuf  = (u16*)(ws + 142606336ull);           // 64 MB  [8192][F] bf16
  // ybuf reuses w1t's 64MB region: w1t is dead after gemm1, ybuf written by gemm2.
  float* ybuf = (float*)(ws + 8388608ull);          // 64 MB  2 slabs of [8192][H] f32
  int*   tki    = (int*)(ws + 209715200ull);
  float* tkw    = (float*)(ws + 209747968ull);
  int*   perm   = (int*)(ws + 209780736ull);
  float* pw     = (float*)(ws + 209813504ull);
  int*   counts = (int*)(ws + 209846272ull);        // counts[8], cursor[8], zsum
  int*   cursor = counts + 8;
  float* zsum   = (float*)(counts + 16);
  int*   islot  = (int*)(ws + 209846400ull);        // 32 KB  [T][2] slot map

  hipMemsetAsync(counts, 0, 128, stream);

  // fused: router (blocks 0..255) + W1 transpose (256..8447) + W2 transpose (8448..16639)
  prep_kernel<<<16640, 256, 0, stream>>>(x, Wr, br, xb, tki, tkw, counts, zsum,
                                         W1, w1t, W2, w2t);
  scatter_kernel<<<T_TOK / 256, 256, 0, stream>>>(tki, tkw, counts, cursor, perm, pw,
                                                  islot, zsum, out + OUT_ELEMS);
  // 8 experts x 16 n-blocks x 16 m-slots (256-row tiles)
  gemm1_kernel<<<2048, 256, 0, stream>>>(xb, w1t, b1, perm, counts, hbuf);
  // 8 experts x 4 n-blocks x 2 K-splits x 16 m-slots
  gemm2_kernel<<<1024, 256, 0, stream>>>(hbuf, w2t, b2, pw, counts, ybuf);
  combine_kernel<<<T_TOK, 256, 0, stream>>>(ybuf, islot, out);
}

// Round 7
// 605.860 us; speedup vs baseline: 1.2546x; 1.2546x over previous
//
#include <hip/hip_runtime.h>
#include <stdint.h>
#include <math.h>

// Problem constants (B=2,S=2048,H=1024,E=8,K=2,F=4096)
#define T_TOK 4096
#define H_DIM 1024
#define E_EXP 8
#define F_DIM 4096
#define NASSIGN (T_TOK * 2)
#define OUT_ELEMS ((size_t)T_TOK * H_DIM)
#define YB_ELEMS ((size_t)8192 * H_DIM)   // one split-K slab: [8192][H] f32
#define TL 257                            // LDS transpose row length (bank-tuned)

typedef unsigned short u16;
typedef __attribute__((ext_vector_type(8))) short short8;   // 8 bf16 = 4 VGPRs
typedef __attribute__((ext_vector_type(4))) short short4v;  // 4 bf16 = 2 VGPRs
typedef __attribute__((ext_vector_type(4))) float f32x4;

__device__ __forceinline__ u16 f2bf(float f) {
  union { float f; uint32_t u; } c; c.f = f;
  uint32_t u = c.u;
  return (u16)((u + 0x7FFFu + ((u >> 16) & 1u)) >> 16);  // RNE
}

// fast erf (Abramowitz-Stegun 7.1.26, |abs err| <= 1.5e-7)
__device__ __forceinline__ float fast_erf(float u) {
  const float au = fabsf(u);
  const float t = __builtin_amdgcn_rcpf(__builtin_fmaf(0.3275911f, au, 1.0f));
  float p = __builtin_fmaf(1.061405429f, t, -1.453152027f);
  p = __builtin_fmaf(p, t, 1.421413741f);
  p = __builtin_fmaf(p, t, -0.284496736f);
  p = __builtin_fmaf(p, t, 0.254829592f);
  p = p * t;
  const float y = __builtin_fmaf(-p, __expf(-au * au), 1.0f);
  return copysignf(y, u);
}

// async global->LDS, 16B per lane. LDS dest is wave-uniform base + lane*16.
__device__ __forceinline__ void gl_lds16(const void* g, void* l) {
  __builtin_amdgcn_global_load_lds(
      (const __attribute__((address_space(1))) uint32_t*)g,
      (__attribute__((address_space(3))) uint32_t*)(uintptr_t)l, 16, 0, 0);
}

// ---------------- fused prep: router + W1 transpose + W2 transpose ----------------
// Transpose reads 64-row x 256-col strips: each wave reads a FULL 1KB contiguous
// row segment per pass (vs 256B bursts at 16KB stride before -- the HBM-efficiency
// fix). LDS [64][TL=257]: phase-2 column reads are 2-way bank-aliased (free);
// phase-1 scalar stores 4-way (1.58x, hidden under HBM latency).
// out: [E][C/64][R/64][64][64] bf16, inner tile [c-local][r-local], r contiguous.
__device__ __forceinline__ void transpose_strip(
    const float* __restrict__ in, u16* __restrict__ out, int R, int C,
    int bx /*256-col strip*/, int by /*64-row tile*/, int bz, u16* tile) {
  const size_t eoff = (size_t)bz * R * C;
  const int wave = threadIdx.x >> 6, lane = threadIdx.x & 63;
  const float* inp = in + eoff + ((size_t)by * 64) * C + bx * 256;
#pragma unroll
  for (int p = 0; p < 16; ++p) {
    const int r = p * 4 + wave;
    const float4 v = *(const float4*)(inp + (size_t)r * C + lane * 4);
    u16* trow = tile + r * TL + lane * 4;
    trow[0] = f2bf(v.x); trow[1] = f2bf(v.y); trow[2] = f2bf(v.z); trow[3] = f2bf(v.w);
  }
  __syncthreads();
  const int cl = threadIdx.x >> 3;          // 0..31 (col within tile, +p*32)
  const int rg = (threadIdx.x & 7) * 8;     // row group
#pragma unroll
  for (int tx = 0; tx < 4; ++tx) {
    u16* op = out + (((size_t)bz * (C >> 6) + bx * 4 + tx) * (R >> 6) + by) * 4096;
#pragma unroll
    for (int p = 0; p < 2; ++p) {
      const int c = cl + p * 32;
      short8 o;
#pragma unroll
      for (int j = 0; j < 8; ++j) o[j] = (short)tile[(rg + j) * TL + tx * 64 + c];
      *(short8*)(op + c * 64 + rg) = o;
    }
  }
}

__global__ __launch_bounds__(256) void prep_kernel(
    const float* __restrict__ x, const float* __restrict__ Wr,
    const float* __restrict__ br, u16* __restrict__ xb,
    int* __restrict__ tki, float* __restrict__ tkw,
    int* __restrict__ counts, float* __restrict__ zsum,
    const float* __restrict__ W1, u16* __restrict__ w1t,
    const float* __restrict__ W2, u16* __restrict__ w2t) {
  __shared__ u16 tile[64 * TL];
  __shared__ int lcnt[8];
  __shared__ float lzv[16];
  const int id = blockIdx.x;

  if (id >= 256) {
    if (id < 2304) {
      const int q = id - 256;   // W1 [E][H][F]: R=H(K), C=F(N); 16x16x8
      transpose_strip(W1, w1t, H_DIM, F_DIM, q & 15, (q >> 4) & 15, q >> 8, tile);
    } else {
      const int q = id - 2304;  // W2 [E][F][H]: R=F(K), C=H(N); 4x64x8
      transpose_strip(W2, w2t, F_DIM, H_DIM, q & 3, (q >> 2) & 63, q >> 8, tile);
    }
    return;
  }

  // ---- router: 16 tokens per block (4 waves x 4 tokens), float4 x loads ----
  const int wave = threadIdx.x >> 6;
  const int lane = threadIdx.x & 63;
  if (threadIdx.x < 8) lcnt[threadIdx.x] = 0;
  __syncthreads();
#pragma unroll
  for (int it = 0; it < 4; ++it) {
    const int t = id * 16 + wave * 4 + it;
    const float* xr = x + (size_t)t * H_DIM;
    u16* xbr = xb + (size_t)t * H_DIM;
    float acc[8];
#pragma unroll
    for (int e = 0; e < 8; ++e) acc[e] = 0.0f;
#pragma unroll
    for (int j = 0; j < 4; ++j) {
      const int h0 = j * 256 + lane * 4;
      const float4 xv = *(const float4*)(xr + h0);
      const float vv[4] = {xv.x, xv.y, xv.z, xv.w};
      short4v pk;
#pragma unroll
      for (int i = 0; i < 4; ++i) {
        pk[i] = (short)f2bf(vv[i]);
        const float4 w0 = *(const float4*)(Wr + (size_t)(h0 + i) * 8);
        const float4 w1 = *(const float4*)(Wr + (size_t)(h0 + i) * 8 + 4);
        acc[0] += vv[i] * w0.x; acc[1] += vv[i] * w0.y;
        acc[2] += vv[i] * w0.z; acc[3] += vv[i] * w0.w;
        acc[4] += vv[i] * w1.x; acc[5] += vv[i] * w1.y;
        acc[6] += vv[i] * w1.z; acc[7] += vv[i] * w1.w;
      }
      *(short4v*)(xbr + h0) = pk;
    }
#pragma unroll
    for (int e = 0; e < 8; ++e) {
      float v = acc[e];
#pragma unroll
      for (int s = 32; s > 0; s >>= 1) v += __shfl_xor(v, s);
      acc[e] = v;
    }
    if (lane == 0) {
      float l[8];
#pragma unroll
      for (int e = 0; e < 8; ++e) l[e] = acc[e] + br[e];
      float mx = l[0];
#pragma unroll
      for (int e = 1; e < 8; ++e) mx = fmaxf(mx, l[e]);
      float p[8], s = 0.0f;
#pragma unroll
      for (int e = 0; e < 8; ++e) { p[e] = __expf(l[e] - mx); s += p[e]; }
      int i0 = 0;
#pragma unroll
      for (int e = 1; e < 8; ++e) if (p[e] > p[i0]) i0 = e;
      int i1 = (i0 == 0) ? 1 : 0;
#pragma unroll
      for (int e = 0; e < 8; ++e) if (e != i1 && e != i0 && p[e] > p[i1]) i1 = e;
      const float ws = p[i0] + p[i1];
      tki[2 * t] = i0; tki[2 * t + 1] = i1;
      tkw[2 * t] = p[i0] / ws; tkw[2 * t + 1] = p[i1] / ws;
      atomicAdd(&lcnt[i0], 1);
      atomicAdd(&lcnt[i1], 1);
      lzv[wave * 4 + it] = mx + logf(s);
    }
  }
  __syncthreads();
  if (threadIdx.x < 8) {
    const int c = lcnt[threadIdx.x];
    if (c) atomicAdd(&counts[threadIdx.x], c);
  }
  if (threadIdx.x == 64) {
    float zs = 0.0f;
#pragma unroll
    for (int i = 0; i < 16; ++i) zs += lzv[i];
    atomicAdd(zsum, zs);
  }
}

// scatter + (block 0) loss. Per-wave ballot aggregation for cursor atomics.
__global__ void scatter_kernel(const int* __restrict__ tki, const float* __restrict__ tkw,
                               const int* __restrict__ counts, int* __restrict__ cursor,
                               int* __restrict__ perm, float* __restrict__ pw,
                               int* __restrict__ islot,
                               const float* __restrict__ zsum, float* __restrict__ out_loss) {
  int offs[8];
  {
    int a = 0;
#pragma unroll
    for (int e = 0; e < 8; ++e) { offs[e] = a; a += counts[e]; }
  }
  const int lane = threadIdx.x & 63;
  const int t = blockIdx.x * 256 + threadIdx.x;
#pragma unroll
  for (int k = 0; k < 2; ++k) {
    const int e = tki[2 * t + k];
    int slot = 0;
#pragma unroll
    for (int ee = 0; ee < 8; ++ee) {
      const unsigned long long mask = __ballot(e == ee);
      if (mask) {
        const int leader = __ffsll(mask) - 1;
        int b = 0;
        if (lane == leader) b = atomicAdd(&cursor[ee], (int)__popcll(mask));
        b = __shfl(b, leader);
        if (e == ee) {
          const int r = (int)__popcll(mask & ((1ull << lane) - 1ull));
          slot = offs[ee] + b + r;
        }
      }
    }
    perm[slot] = t;
    pw[slot] = tkw[2 * t + k];
    islot[2 * t + k] = slot;
  }
  if (blockIdx.x == 0 && threadIdx.x == 0) {
    float aux = 0.0f;
#pragma unroll
    for (int e = 0; e < 8; ++e) {
      const float d = (float)counts[e] / (float)NASSIGN - 0.125f;
      aux += d * d;
    }
    aux *= (1.0f / 8.0f);
    out_loss[0] = 0.01f * aux + 0.001f * (zsum[0] / (float)T_TOK);
  }
}

// ---------------- grouped GEMMs: 128x128 tile, BK=64, XOR-swizzled staging ----------------
// (round-2/5 structure -- best measured; both 256^2 rebuilds regressed)
// id&7 = expert -> XCD affinity.

// h[slot][F] = gelu( xb[perm[slot]] @ W1t[e]^T + b1[e] )  (bf16 out)
__global__ __launch_bounds__(256, 4) void gemm1_kernel(
    const u16* __restrict__ xb, const u16* __restrict__ w1t,
    const float* __restrict__ b1, const int* __restrict__ perm,
    const int* __restrict__ cnts, u16* __restrict__ hbuf) {
  const int id = blockIdx.x;
  const int e = id & 7;               // XCD group
  const int wq = id >> 3;
  const int n0 = (wq & 31) << 7;      // 32 n-blocks
  const int m0 = (wq >> 5) << 7;      // m outer: live blocks dispatch first
  int cnt, off;
  {
    int a = 0, c = 0;
#pragma unroll
    for (int i = 0; i < 8; ++i) { const int ci = cnts[i]; if (i < e) a += ci; if (i == e) c = ci; }
    cnt = c; off = a;
  }
  if (m0 >= cnt) return;

  __shared__ __align__(16) u16 smem[16384];   // As 8192 + Bs 8192; epilogue reuses all 32KB
  u16* As = smem;
  u16* Bs = smem + 8192;

  const int tid = threadIdx.x;
  const int rbase = tid >> 3;
  const int kc = ((tid & 7) ^ (rbase & 7)) * 8;

  const u16* ap[4];
#pragma unroll
  for (int l = 0; l < 4; ++l) {
    int ra = m0 + rbase + l * 32; if (ra > cnt - 1) ra = cnt - 1;
    ap[l] = xb + (size_t)perm[off + ra] * H_DIM + kc;
  }
  const u16* bp0 = w1t + ((((size_t)e * (F_DIM >> 6) + (n0 >> 6)) * (H_DIM >> 6)) << 12)
                 + rbase * 64 + kc;
  const size_t bnt = (size_t)(H_DIM >> 6) << 12;

  const int wave = tid >> 6, lane = tid & 63;
  const int wm = (wave >> 1) * 64, wn = (wave & 1) * 64;
  const int lr = lane & 15, q = lane >> 4;
  const int qs0 = q ^ (lr & 7), qs1 = (4 + q) ^ (lr & 7);

  f32x4 acc[4][4];
#pragma unroll
  for (int i = 0; i < 4; ++i)
#pragma unroll
    for (int j = 0; j < 4; ++j) acc[i][j] = (f32x4)0.0f;

  const short8* Afr = (const short8*)As;
  const short8* Bfr = (const short8*)Bs;

  for (int k0 = 0; k0 < (H_DIM >> 6); ++k0) {
    gl_lds16(ap[0], &As[(size_t)tid * 8]);
    gl_lds16(ap[1], &As[(size_t)(tid + 256) * 8]);
    gl_lds16(ap[2], &As[(size_t)(tid + 512) * 8]);
    gl_lds16(ap[3], &As[(size_t)(tid + 768) * 8]);
    gl_lds16(bp0,              &Bs[(size_t)tid * 8]);
    gl_lds16(bp0 + 2048,       &Bs[(size_t)(tid + 256) * 8]);
    gl_lds16(bp0 + bnt,        &Bs[(size_t)(tid + 512) * 8]);
    gl_lds16(bp0 + bnt + 2048, &Bs[(size_t)(tid + 768) * 8]);
#pragma unroll
    for (int l = 0; l < 4; ++l) ap[l] += 64;
    bp0 += 4096;
    __syncthreads();
#pragma unroll
    for (int s = 0; s < 2; ++s) {
      const int qs = s ? qs1 : qs0;
      short8 a[4], b[4];
#pragma unroll
      for (int i = 0; i < 4; ++i) a[i] = Afr[(wm + i * 16 + lr) * 8 + qs];
#pragma unroll
      for (int j = 0; j < 4; ++j) b[j] = Bfr[(wn + j * 16 + lr) * 8 + qs];
#pragma unroll
      for (int i = 0; i < 4; ++i)
#pragma unroll
        for (int j = 0; j < 4; ++j)
          acc[i][j] = __builtin_amdgcn_mfma_f32_16x16x32_bf16(a[i], b[j], acc[i][j], 0, 0, 0);
    }
    __syncthreads();
  }

  // Epilogue: bias+gelu (fast erf) -> bf16 -> LDS (XOR col swizzle) -> 16B stores.
#pragma unroll
  for (int i = 0; i < 4; ++i) {
#pragma unroll
    for (int rr = 0; rr < 4; ++rr) {
      const int row = wm + i * 16 + q * 4 + rr;
#pragma unroll
      for (int j = 0; j < 4; ++j) {
        const int col = wn + j * 16 + lr;
        const float v = acc[i][j][rr] + b1[e * F_DIM + n0 + col];
        const float g = 0.5f * v * (1.0f + fast_erf(v * 0.70710678118654752f));
        smem[(row << 7) + (col ^ (q << 4))] = f2bf(g);
      }
    }
  }
  __syncthreads();
#pragma unroll
  for (int p = 0; p < 8; ++p) {
    const int ml = p * 16 + (tid >> 4);
    const int nl = (tid & 15) * 8;
    const int m = m0 + ml;
    if (m < cnt) {
      const int qq = (ml >> 2) & 3;
      *(short8*)(hbuf + (size_t)(off + m) * F_DIM + n0 + nl) =
          *(const short8*)(smem + (ml << 7) + (nl ^ (qq << 4)));
    }
  }
}

// ybuf[ks][slot] = w_slot * (h[slot] @ W2t[e]^T [k-half ks] + (ks==0)*b2[e])
// split-K=2 over separate slabs -> no atomics.
__global__ __launch_bounds__(256, 4) void gemm2_kernel(
    const u16* __restrict__ hbuf, const u16* __restrict__ w2t,
    const float* __restrict__ b2, const float* __restrict__ pw,
    const int* __restrict__ cnts, float* __restrict__ ybuf) {
  const int id = blockIdx.x;
  const int e = id & 7;               // XCD group
  const int wq = id >> 3;
  const int n0 = (wq & 7) << 7;       // 8 n-blocks
  const int ks = (wq >> 3) & 1;       // 2 K-splits (2048 each)
  const int m0 = (wq >> 4) << 7;      // m outer
  int cnt, off;
  {
    int a = 0, c = 0;
#pragma unroll
    for (int i = 0; i < 8; ++i) { const int ci = cnts[i]; if (i < e) a += ci; if (i == e) c = ci; }
    cnt = c; off = a;
  }
  if (m0 >= cnt) return;

  __shared__ __align__(16) u16 As[128 * 64];
  __shared__ __align__(16) u16 Bs[128 * 64];

  const int tid = threadIdx.x;
  const int rbase = tid >> 3;
  const int kc = ((tid & 7) ^ (rbase & 7)) * 8;

  const u16* ap[4];
#pragma unroll
  for (int l = 0; l < 4; ++l) {
    int ra = m0 + rbase + l * 32; if (ra > cnt - 1) ra = cnt - 1;
    ap[l] = hbuf + (size_t)(off + ra) * F_DIM + (ks << 11) + kc;
  }
  const u16* bp0 = w2t + ((((size_t)e * (H_DIM >> 6) + (n0 >> 6)) * (F_DIM >> 6)) << 12)
                 + ((size_t)(ks << 5) << 12) + rbase * 64 + kc;
  const size_t bnt = (size_t)(F_DIM >> 6) << 12;

  const int wave = tid >> 6, lane = tid & 63;
  const int wm = (wave >> 1) * 64, wn = (wave & 1) * 64;
  const int lr = lane & 15, q = lane >> 4;
  const int qs0 = q ^ (lr & 7), qs1 = (4 + q) ^ (lr & 7);

  f32x4 acc[4][4];
#pragma unroll
  for (int i = 0; i < 4; ++i)
#pragma unroll
    for (int j = 0; j < 4; ++j) acc[i][j] = (f32x4)0.0f;

  const short8* Afr = (const short8*)As;
  const short8* Bfr = (const short8*)Bs;

  for (int k0 = 0; k0 < 32; ++k0) {   // 2048 / 64, half of K
    gl_lds16(ap[0], &As[(size_t)tid * 8]);
    gl_lds16(ap[1], &As[(size_t)(tid + 256) * 8]);
    gl_lds16(ap[2], &As[(size_t)(tid + 512) * 8]);
    gl_lds16(ap[3], &As[(size_t)(tid + 768) * 8]);
    gl_lds16(bp0,              &Bs[(size_t)tid * 8]);
    gl_lds16(bp0 + 2048,       &Bs[(size_t)(tid + 256) * 8]);
    gl_lds16(bp0 + bnt,        &Bs[(size_t)(tid + 512) * 8]);
    gl_lds16(bp0 + bnt + 2048, &Bs[(size_t)(tid + 768) * 8]);
#pragma unroll
    for (int l = 0; l < 4; ++l) ap[l] += 64;
    bp0 += 4096;
    __syncthreads();
#pragma unroll
    for (int s = 0; s < 2; ++s) {
      const int qs = s ? qs1 : qs0;
      short8 a[4], b[4];
#pragma unroll
      for (int i = 0; i < 4; ++i) a[i] = Afr[(wm + i * 16 + lr) * 8 + qs];
#pragma unroll
      for (int j = 0; j < 4; ++j) b[j] = Bfr[(wn + j * 16 + lr) * 8 + qs];
#pragma unroll
      for (int i = 0; i < 4; ++i)
#pragma unroll
        for (int j = 0; j < 4; ++j)
          acc[i][j] = __builtin_amdgcn_mfma_f32_16x16x32_bf16(a[i], b[j], acc[i][j], 0, 0, 0);
    }
    __syncthreads();
  }

  // Epilogue: per-slot weighted partial, plain f32 stores into slab ks.
  float* yb = ybuf + (size_t)ks * YB_ELEMS;
#pragma unroll
  for (int i = 0; i < 4; ++i) {
#pragma unroll
    for (int rr = 0; rr < 4; ++rr) {
      const int m = m0 + wm + i * 16 + q * 4 + rr;
      if (m < cnt) {
        const int slot = off + m;
        const float w = pw[slot];
        float* orow = yb + (size_t)slot * H_DIM;
#pragma unroll
        for (int j = 0; j < 4; ++j) {
          const int col = n0 + wn + j * 16 + lr;
          float y = acc[i][j][rr];
          if (ks == 0) y += b2[e * H_DIM + col];
          orow[col] = w * y;
        }
      }
    }
  }
}

// out[t] = sum over k of (ybuf0[slot_k] + ybuf1[slot_k])
__global__ __launch_bounds__(256) void combine_kernel(
    const float* __restrict__ ybuf, const int* __restrict__ islot,
    float* __restrict__ out) {
  const int t = blockIdx.x;
  const int s0 = islot[2 * t];
  const int s1 = islot[2 * t + 1];
  const int c = threadIdx.x * 4;
  const float4 a0 = *(const float4*)(ybuf + (size_t)s0 * H_DIM + c);
  const float4 a1 = *(const float4*)(ybuf + YB_ELEMS + (size_t)s0 * H_DIM + c);
  const float4 b0 = *(const float4*)(ybuf + (size_t)s1 * H_DIM + c);
  const float4 b1 = *(const float4*)(ybuf + YB_ELEMS + (size_t)s1 * H_DIM + c);
  float4 r;
  r.x = a0.x + a1.x + b0.x + b1.x;
  r.y = a0.y + a1.y + b0.y + b1.y;
  r.z = a0.z + a1.z + b0.z + b1.z;
  r.w = a0.w + a1.w + b0.w + b1.w;
  *(float4*)(out + (size_t)t * H_DIM + c) = r;
}

// ---------------- launch ----------------

extern "C" void kernel_launch(void* const* d_in, const int* in_sizes, int n_in,
                              void* d_out, int out_size, void* d_ws, size_t ws_size,
                              hipStream_t stream) {
  const float* x  = (const float*)d_in[0];
  const float* Wr = (const float*)d_in[1];
  const float* br = (const float*)d_in[2];
  const float* W1 = (const float*)d_in[3];
  const float* b1 = (const float*)d_in[4];
  const float* W2 = (const float*)d_in[5];
  const float* b2 = (const float*)d_in[6];
  float* out = (float*)d_out;

  // workspace layout (~210 MB)
  char* ws = (char*)d_ws;
  u16* xb    = (u16*)(ws);                          // 8 MB
  u16* w1t   = (u16*)(ws + 8388608ull);             // 64 MB  tiled [E][F/64][H/64][64][64]
  u16* w2t   = (u16*)(ws + 75497472ull);            // 64 MB  tiled [E][H/64][F/64][64][64]
  u16* hbuf  = (u16*)(ws + 142606336ull);           // 64 MB  [8192][F] bf16
  // ybuf reuses w1t's 64MB region: w1t is dead after gemm1, ybuf written by gemm2.
  float* ybuf = (float*)(ws + 8388608ull);          // 64 MB  2 slabs of [8192][H] f32
  int*   tki    = (int*)(ws + 209715200ull);
  float* tkw    = (float*)(ws + 209747968ull);
  int*   perm   = (int*)(ws + 209780736ull);
  float* pw     = (float*)(ws + 209813504ull);
  int*   counts = (int*)(ws + 209846272ull);        // counts[8], cursor[8], zsum
  int*   cursor = counts + 8;
  float* zsum   = (float*)(counts + 16);
  int*   islot  = (int*)(ws + 209846400ull);        // 32 KB  [T][2] slot map

  hipMemsetAsync(counts, 0, 128, stream);

  // fused: router (0..255) + W1 strips (256..2303) + W2 strips (2304..4351)
  prep_kernel<<<4352, 256, 0, stream>>>(x, Wr, br, xb, tki, tkw, counts, zsum,
                                        W1, w1t, W2, w2t);
  scatter_kernel<<<T_TOK / 256, 256, 0, stream>>>(tki, tkw, counts, cursor, perm, pw,
                                                  islot, zsum, out + OUT_ELEMS);
  gemm1_kernel<<<8192, 256, 0, stream>>>(xb, w1t, b1, perm, counts, hbuf);
  // 8 experts x 8 n-blocks x 2 K-splits x up to 32 m-blocks
  gemm2_kernel<<<4096, 256, 0, stream>>>(hbuf, w2t, b2, pw, counts, ybuf);
  combine_kernel<<<T_TOK, 256, 0, stream>>>(ybuf, islot, out);
}

// Round 8
// 586.234 us; speedup vs baseline: 1.2966x; 1.0335x over previous
//
#include <hip/hip_runtime.h>
#include <stdint.h>
#include <math.h>

// Problem constants (B=2,S=2048,H=1024,E=8,K=2,F=4096)
#define T_TOK 4096
#define H_DIM 1024
#define E_EXP 8
#define F_DIM 4096
#define NASSIGN (T_TOK * 2)
#define OUT_ELEMS ((size_t)T_TOK * H_DIM)
#define YB_ELEMS ((size_t)8192 * H_DIM)   // one split-K slab: [8192][H] f32
#define TL 257                            // LDS transpose row length (bank-tuned)

typedef unsigned short u16;
typedef __attribute__((ext_vector_type(8))) short short8;   // 8 bf16 = 4 VGPRs
typedef __attribute__((ext_vector_type(4))) short short4v;  // 4 bf16 = 2 VGPRs
typedef __attribute__((ext_vector_type(4))) float f32x4;

__device__ __forceinline__ u16 f2bf(float f) {
  union { float f; uint32_t u; } c; c.f = f;
  uint32_t u = c.u;
  return (u16)((u + 0x7FFFu + ((u >> 16) & 1u)) >> 16);  // RNE
}

// fast erf (Abramowitz-Stegun 7.1.26, |abs err| <= 1.5e-7)
__device__ __forceinline__ float fast_erf(float u) {
  const float au = fabsf(u);
  const float t = __builtin_amdgcn_rcpf(__builtin_fmaf(0.3275911f, au, 1.0f));
  float p = __builtin_fmaf(1.061405429f, t, -1.453152027f);
  p = __builtin_fmaf(p, t, 1.421413741f);
  p = __builtin_fmaf(p, t, -0.284496736f);
  p = __builtin_fmaf(p, t, 0.254829592f);
  p = p * t;
  const float y = __builtin_fmaf(-p, __expf(-au * au), 1.0f);
  return copysignf(y, u);
}

// async global->LDS, 16B per lane. LDS dest is wave-uniform base + lane*16.
__device__ __forceinline__ void gl_lds16(const void* g, void* l) {
  __builtin_amdgcn_global_load_lds(
      (const __attribute__((address_space(1))) uint32_t*)g,
      (__attribute__((address_space(3))) uint32_t*)(uintptr_t)l, 16, 0, 0);
}

// ---------------- fused prep: router + W1 transpose + W2 transpose ----------------
__device__ __forceinline__ void transpose_strip(
    const float* __restrict__ in, u16* __restrict__ out, int R, int C,
    int bx /*256-col strip*/, int by /*64-row tile*/, int bz, u16* tile) {
  const size_t eoff = (size_t)bz * R * C;
  const int wave = threadIdx.x >> 6, lane = threadIdx.x & 63;
  const float* inp = in + eoff + ((size_t)by * 64) * C + bx * 256;
#pragma unroll
  for (int p = 0; p < 16; ++p) {
    const int r = p * 4 + wave;
    const float4 v = *(const float4*)(inp + (size_t)r * C + lane * 4);
    u16* trow = tile + r * TL + lane * 4;
    trow[0] = f2bf(v.x); trow[1] = f2bf(v.y); trow[2] = f2bf(v.z); trow[3] = f2bf(v.w);
  }
  __syncthreads();
  const int cl = threadIdx.x >> 3;          // 0..31 (col within tile, +p*32)
  const int rg = (threadIdx.x & 7) * 8;     // row group
#pragma unroll
  for (int tx = 0; tx < 4; ++tx) {
    u16* op = out + (((size_t)bz * (C >> 6) + bx * 4 + tx) * (R >> 6) + by) * 4096;
#pragma unroll
    for (int p = 0; p < 2; ++p) {
      const int c = cl + p * 32;
      short8 o;
#pragma unroll
      for (int j = 0; j < 8; ++j) o[j] = (short)tile[(rg + j) * TL + tx * 64 + c];
      *(short8*)(op + c * 64 + rg) = o;
    }
  }
}

__global__ __launch_bounds__(256) void prep_kernel(
    const float* __restrict__ x, const float* __restrict__ Wr,
    const float* __restrict__ br, u16* __restrict__ xb,
    int* __restrict__ tki, float* __restrict__ tkw,
    int* __restrict__ counts, float* __restrict__ zsum,
    const float* __restrict__ W1, u16* __restrict__ w1t,
    const float* __restrict__ W2, u16* __restrict__ w2t) {
  __shared__ u16 tile[64 * TL];
  __shared__ int lcnt[8];
  __shared__ float lzv[16];
  const int id = blockIdx.x;

  if (id >= 256) {
    if (id < 2304) {
      const int q = id - 256;   // W1 [E][H][F]: R=H(K), C=F(N); 16x16x8
      transpose_strip(W1, w1t, H_DIM, F_DIM, q & 15, (q >> 4) & 15, q >> 8, tile);
    } else {
      const int q = id - 2304;  // W2 [E][F][H]: R=F(K), C=H(N); 4x64x8
      transpose_strip(W2, w2t, F_DIM, H_DIM, q & 3, (q >> 2) & 63, q >> 8, tile);
    }
    return;
  }

  // ---- router: 16 tokens per block (4 waves x 4 tokens), float4 x loads ----
  const int wave = threadIdx.x >> 6;
  const int lane = threadIdx.x & 63;
  if (threadIdx.x < 8) lcnt[threadIdx.x] = 0;
  __syncthreads();
#pragma unroll
  for (int it = 0; it < 4; ++it) {
    const int t = id * 16 + wave * 4 + it;
    const float* xr = x + (size_t)t * H_DIM;
    u16* xbr = xb + (size_t)t * H_DIM;
    float acc[8];
#pragma unroll
    for (int e = 0; e < 8; ++e) acc[e] = 0.0f;
#pragma unroll
    for (int j = 0; j < 4; ++j) {
      const int h0 = j * 256 + lane * 4;
      const float4 xv = *(const float4*)(xr + h0);
      const float vv[4] = {xv.x, xv.y, xv.z, xv.w};
      short4v pk;
#pragma unroll
      for (int i = 0; i < 4; ++i) {
        pk[i] = (short)f2bf(vv[i]);
        const float4 w0 = *(const float4*)(Wr + (size_t)(h0 + i) * 8);
        const float4 w1 = *(const float4*)(Wr + (size_t)(h0 + i) * 8 + 4);
        acc[0] += vv[i] * w0.x; acc[1] += vv[i] * w0.y;
        acc[2] += vv[i] * w0.z; acc[3] += vv[i] * w0.w;
        acc[4] += vv[i] * w1.x; acc[5] += vv[i] * w1.y;
        acc[6] += vv[i] * w1.z; acc[7] += vv[i] * w1.w;
      }
      *(short4v*)(xbr + h0) = pk;
    }
#pragma unroll
    for (int e = 0; e < 8; ++e) {
      float v = acc[e];
#pragma unroll
      for (int s = 32; s > 0; s >>= 1) v += __shfl_xor(v, s);
      acc[e] = v;
    }
    if (lane == 0) {
      float l[8];
#pragma unroll
      for (int e = 0; e < 8; ++e) l[e] = acc[e] + br[e];
      float mx = l[0];
#pragma unroll
      for (int e = 1; e < 8; ++e) mx = fmaxf(mx, l[e]);
      float p[8], s = 0.0f;
#pragma unroll
      for (int e = 0; e < 8; ++e) { p[e] = __expf(l[e] - mx); s += p[e]; }
      int i0 = 0;
#pragma unroll
      for (int e = 1; e < 8; ++e) if (p[e] > p[i0]) i0 = e;
      int i1 = (i0 == 0) ? 1 : 0;
#pragma unroll
      for (int e = 0; e < 8; ++e) if (e != i1 && e != i0 && p[e] > p[i1]) i1 = e;
      const float ws = p[i0] + p[i1];
      tki[2 * t] = i0; tki[2 * t + 1] = i1;
      tkw[2 * t] = p[i0] / ws; tkw[2 * t + 1] = p[i1] / ws;
      atomicAdd(&lcnt[i0], 1);
      atomicAdd(&lcnt[i1], 1);
      lzv[wave * 4 + it] = mx + logf(s);
    }
  }
  __syncthreads();
  if (threadIdx.x < 8) {
    const int c = lcnt[threadIdx.x];
    if (c) atomicAdd(&counts[threadIdx.x], c);
  }
  if (threadIdx.x == 64) {
    float zs = 0.0f;
#pragma unroll
    for (int i = 0; i < 16; ++i) zs += lzv[i];
    atomicAdd(zsum, zs);
  }
}

// scatter + (block 0) loss. Per-wave ballot aggregation for cursor atomics.
__global__ void scatter_kernel(const int* __restrict__ tki, const float* __restrict__ tkw,
                               const int* __restrict__ counts, int* __restrict__ cursor,
                               int* __restrict__ perm, float* __restrict__ pw,
                               int* __restrict__ islot,
                               const float* __restrict__ zsum, float* __restrict__ out_loss) {
  int offs[8];
  {
    int a = 0;
#pragma unroll
    for (int e = 0; e < 8; ++e) { offs[e] = a; a += counts[e]; }
  }
  const int lane = threadIdx.x & 63;
  const int t = blockIdx.x * 256 + threadIdx.x;
#pragma unroll
  for (int k = 0; k < 2; ++k) {
    const int e = tki[2 * t + k];
    int slot = 0;
#pragma unroll
    for (int ee = 0; ee < 8; ++ee) {
      const unsigned long long mask = __ballot(e == ee);
      if (mask) {
        const int leader = __ffsll(mask) - 1;
        int b = 0;
        if (lane == leader) b = atomicAdd(&cursor[ee], (int)__popcll(mask));
        b = __shfl(b, leader);
        if (e == ee) {
          const int r = (int)__popcll(mask & ((1ull << lane) - 1ull));
          slot = offs[ee] + b + r;
        }
      }
    }
    perm[slot] = t;
    pw[slot] = tkw[2 * t + k];
    islot[2 * t + k] = slot;
  }
  if (blockIdx.x == 0 && threadIdx.x == 0) {
    float aux = 0.0f;
#pragma unroll
    for (int e = 0; e < 8; ++e) {
      const float d = (float)counts[e] / (float)NASSIGN - 0.125f;
      aux += d * d;
    }
    aux *= (1.0f / 8.0f);
    out_loss[0] = 0.01f * aux + 0.001f * (zsum[0] / (float)T_TOK);
  }
}

// ---------------- grouped GEMMs: 256x128 tile, wave tile 128x64, BK=64 ----------------
// LDS-BW model: fragment reads scale (rm+rn), MFMAs rm*rn. Old 4x4 wave: 512
// LDS-B/MFMA (measured MfmaUtil 20%). New 8x4 wave: 384 B/MFMA, acc=128 VGPR
// keeps 2 waves/SIMD (r6's 8x8 died at 1 wave/SIMD). Same proven swizzle; no
// sync-structure change. id&7 = expert -> XCD affinity.

// h[slot][F] = gelu( xb[perm[slot]] @ W1t[e]^T + b1[e] )  (bf16 out)
__global__ __launch_bounds__(256, 2) void gemm1_kernel(
    const u16* __restrict__ xb, const u16* __restrict__ w1t,
    const float* __restrict__ b1, const int* __restrict__ perm,
    const int* __restrict__ cnts, u16* __restrict__ hbuf) {
  const int id = blockIdx.x;
  const int e = id & 7;               // XCD group
  const int wq = id >> 3;
  const int n0 = (wq & 31) << 7;      // 32 n-blocks of 128
  const int m0 = (wq >> 5) << 8;      // 16 m-slots of 256; live blocks first
  int cnt, off;
  {
    int a = 0, c = 0;
#pragma unroll
    for (int i = 0; i < 8; ++i) { const int ci = cnts[i]; if (i < e) a += ci; if (i == e) c = ci; }
    cnt = c; off = a;
  }
  if (m0 >= cnt) return;

  __shared__ __align__(16) u16 smem[24576];   // As 32KB (256x64) + Bs 16KB (128x64)
  u16* As = smem;
  u16* Bs = smem + 16384;

  const int tid = threadIdx.x;
  const int rbase = tid >> 3;
  const int kc = ((tid & 7) ^ (rbase & 7)) * 8;

  const u16* ap[8];
#pragma unroll
  for (int l = 0; l < 8; ++l) {
    int ra = m0 + rbase + l * 32; if (ra > cnt - 1) ra = cnt - 1;
    ap[l] = xb + (size_t)perm[off + ra] * H_DIM + kc;
  }
  const u16* bp0 = w1t + ((((size_t)e * (F_DIM >> 6) + (n0 >> 6)) * (H_DIM >> 6)) << 12)
                 + rbase * 64 + kc;
  const size_t bnt = (size_t)(H_DIM >> 6) << 12;

  const int wave = tid >> 6, lane = tid & 63;
  const int wm = (wave >> 1) * 128, wn = (wave & 1) * 64;
  const int lr = lane & 15, q = lane >> 4;
  const int qs0 = q ^ (lr & 7), qs1 = (4 + q) ^ (lr & 7);

  f32x4 acc[8][4];
#pragma unroll
  for (int i = 0; i < 8; ++i)
#pragma unroll
    for (int j = 0; j < 4; ++j) acc[i][j] = (f32x4)0.0f;

  const short8* Afr = (const short8*)As;
  const short8* Bfr = (const short8*)Bs;

  for (int k0 = 0; k0 < (H_DIM >> 6); ++k0) {
#pragma unroll
    for (int l = 0; l < 8; ++l) {
      gl_lds16(ap[l], &As[(size_t)(tid + l * 256) * 8]);
      ap[l] += 64;
    }
    gl_lds16(bp0,              &Bs[(size_t)tid * 8]);
    gl_lds16(bp0 + 2048,       &Bs[(size_t)(tid + 256) * 8]);
    gl_lds16(bp0 + bnt,        &Bs[(size_t)(tid + 512) * 8]);
    gl_lds16(bp0 + bnt + 2048, &Bs[(size_t)(tid + 768) * 8]);
    bp0 += 4096;
    __syncthreads();
#pragma unroll
    for (int s = 0; s < 2; ++s) {
      const int qs = s ? qs1 : qs0;
      short8 a[8], b[4];
#pragma unroll
      for (int i = 0; i < 8; ++i) a[i] = Afr[(wm + i * 16 + lr) * 8 + qs];
#pragma unroll
      for (int j = 0; j < 4; ++j) b[j] = Bfr[(wn + j * 16 + lr) * 8 + qs];
#pragma unroll
      for (int i = 0; i < 8; ++i)
#pragma unroll
        for (int j = 0; j < 4; ++j)
          acc[i][j] = __builtin_amdgcn_mfma_f32_16x16x32_bf16(a[i], b[j], acc[i][j], 0, 0, 0);
    }
    __syncthreads();
  }

  // Epilogue: two 128-row passes through 32KB of smem (proven swizzle).
#pragma unroll
  for (int h = 0; h < 2; ++h) {
    if ((wave >> 1) == h) {
#pragma unroll
      for (int i = 0; i < 8; ++i) {
#pragma unroll
        for (int rr = 0; rr < 4; ++rr) {
          const int rloc = i * 16 + q * 4 + rr;     // 0..127
#pragma unroll
          for (int j = 0; j < 4; ++j) {
            const int col = wn + j * 16 + lr;       // 0..127
            const float v = acc[i][j][rr] + b1[e * F_DIM + n0 + col];
            const float g = 0.5f * v * (1.0f + fast_erf(v * 0.70710678118654752f));
            smem[(rloc << 7) + (col ^ (q << 4))] = f2bf(g);
          }
        }
      }
    }
    __syncthreads();
#pragma unroll
    for (int p = 0; p < 8; ++p) {
      const int ml = p * 16 + (tid >> 4);
      const int nl = (tid & 15) * 8;
      const int m = m0 + h * 128 + ml;
      if (m < cnt) {
        const int qq = (ml >> 2) & 3;
        *(short8*)(hbuf + (size_t)(off + m) * F_DIM + n0 + nl) =
            *(const short8*)(smem + (ml << 7) + (nl ^ (qq << 4)));
      }
    }
    __syncthreads();
  }
}

// ybuf[ks][slot] = w_slot * (h[slot] @ W2t[e]^T [k-half ks] + (ks==0)*b2[e])
// split-K=2 over separate slabs -> no atomics.
__global__ __launch_bounds__(256, 2) void gemm2_kernel(
    const u16* __restrict__ hbuf, const u16* __restrict__ w2t,
    const float* __restrict__ b2, const float* __restrict__ pw,
    const int* __restrict__ cnts, float* __restrict__ ybuf) {
  const int id = blockIdx.x;
  const int e = id & 7;               // XCD group
  const int wq = id >> 3;
  const int n0 = (wq & 7) << 7;       // 8 n-blocks of 128
  const int ks = (wq >> 3) & 1;       // 2 K-splits (2048 each)
  const int m0 = (wq >> 4) << 8;      // 16 m-slots of 256
  int cnt, off;
  {
    int a = 0, c = 0;
#pragma unroll
    for (int i = 0; i < 8; ++i) { const int ci = cnts[i]; if (i < e) a += ci; if (i == e) c = ci; }
    cnt = c; off = a;
  }
  if (m0 >= cnt) return;

  __shared__ __align__(16) u16 smem[24576];   // As 256x64 + Bs 128x64
  u16* As = smem;
  u16* Bs = smem + 16384;

  const int tid = threadIdx.x;
  const int rbase = tid >> 3;
  const int kc = ((tid & 7) ^ (rbase & 7)) * 8;

  const u16* ap[8];
#pragma unroll
  for (int l = 0; l < 8; ++l) {
    int ra = m0 + rbase + l * 32; if (ra > cnt - 1) ra = cnt - 1;
    ap[l] = hbuf + (size_t)(off + ra) * F_DIM + (ks << 11) + kc;
  }
  const u16* bp0 = w2t + ((((size_t)e * (H_DIM >> 6) + (n0 >> 6)) * (F_DIM >> 6)) << 12)
                 + ((size_t)(ks << 5) << 12) + rbase * 64 + kc;
  const size_t bnt = (size_t)(F_DIM >> 6) << 12;

  const int wave = tid >> 6, lane = tid & 63;
  const int wm = (wave >> 1) * 128, wn = (wave & 1) * 64;
  const int lr = lane & 15, q = lane >> 4;
  const int qs0 = q ^ (lr & 7), qs1 = (4 + q) ^ (lr & 7);

  f32x4 acc[8][4];
#pragma unroll
  for (int i = 0; i < 8; ++i)
#pragma unroll
    for (int j = 0; j < 4; ++j) acc[i][j] = (f32x4)0.0f;

  const short8* Afr = (const short8*)As;
  const short8* Bfr = (const short8*)Bs;

  for (int k0 = 0; k0 < 32; ++k0) {   // 2048 / 64, half of K
#pragma unroll
    for (int l = 0; l < 8; ++l) {
      gl_lds16(ap[l], &As[(size_t)(tid + l * 256) * 8]);
      ap[l] += 64;
    }
    gl_lds16(bp0,              &Bs[(size_t)tid * 8]);
    gl_lds16(bp0 + 2048,       &Bs[(size_t)(tid + 256) * 8]);
    gl_lds16(bp0 + bnt,        &Bs[(size_t)(tid + 512) * 8]);
    gl_lds16(bp0 + bnt + 2048, &Bs[(size_t)(tid + 768) * 8]);
    bp0 += 4096;
    __syncthreads();
#pragma unroll
    for (int s = 0; s < 2; ++s) {
      const int qs = s ? qs1 : qs0;
      short8 a[8], b[4];
#pragma unroll
      for (int i = 0; i < 8; ++i) a[i] = Afr[(wm + i * 16 + lr) * 8 + qs];
#pragma unroll
      for (int j = 0; j < 4; ++j) b[j] = Bfr[(wn + j * 16 + lr) * 8 + qs];
#pragma unroll
      for (int i = 0; i < 8; ++i)
#pragma unroll
        for (int j = 0; j < 4; ++j)
          acc[i][j] = __builtin_amdgcn_mfma_f32_16x16x32_bf16(a[i], b[j], acc[i][j], 0, 0, 0);
    }
    __syncthreads();
  }

  // Epilogue: per-slot weighted partial, plain f32 stores into slab ks.
  float* yb = ybuf + (size_t)ks * YB_ELEMS;
#pragma unroll
  for (int i = 0; i < 8; ++i) {
#pragma unroll
    for (int rr = 0; rr < 4; ++rr) {
      const int m = m0 + wm + i * 16 + q * 4 + rr;
      if (m < cnt) {
        const int slot = off + m;
        const float w = pw[slot];
        float* orow = yb + (size_t)slot * H_DIM;
#pragma unroll
        for (int j = 0; j < 4; ++j) {
          const int col = n0 + wn + j * 16 + lr;
          float y = acc[i][j][rr];
          if (ks == 0) y += b2[e * H_DIM + col];
          orow[col] = w * y;
        }
      }
    }
  }
}

// out[t] = sum over k of (ybuf0[slot_k] + ybuf1[slot_k])
__global__ __launch_bounds__(256) void combine_kernel(
    const float* __restrict__ ybuf, const int* __restrict__ islot,
    float* __restrict__ out) {
  const int t = blockIdx.x;
  const int s0 = islot[2 * t];
  const int s1 = islot[2 * t + 1];
  const int c = threadIdx.x * 4;
  const float4 a0 = *(const float4*)(ybuf + (size_t)s0 * H_DIM + c);
  const float4 a1 = *(const float4*)(ybuf + YB_ELEMS + (size_t)s0 * H_DIM + c);
  const float4 b0 = *(const float4*)(ybuf + (size_t)s1 * H_DIM + c);
  const float4 b1 = *(const float4*)(ybuf + YB_ELEMS + (size_t)s1 * H_DIM + c);
  float4 r;
  r.x = a0.x + a1.x + b0.x + b1.x;
  r.y = a0.y + a1.y + b0.y + b1.y;
  r.z = a0.z + a1.z + b0.z + b1.z;
  r.w = a0.w + a1.w + b0.w + b1.w;
  *(float4*)(out + (size_t)t * H_DIM + c) = r;
}

// ---------------- launch ----------------

extern "C" void kernel_launch(void* const* d_in, const int* in_sizes, int n_in,
                              void* d_out, int out_size, void* d_ws, size_t ws_size,
                              hipStream_t stream) {
  const float* x  = (const float*)d_in[0];
  const float* Wr = (const float*)d_in[1];
  const float* br = (const float*)d_in[2];
  const float* W1 = (const float*)d_in[3];
  const float* b1 = (const float*)d_in[4];
  const float* W2 = (const float*)d_in[5];
  const float* b2 = (const float*)d_in[6];
  float* out = (float*)d_out;

  // workspace layout (~210 MB)
  char* ws = (char*)d_ws;
  u16* xb    = (u16*)(ws);                          // 8 MB
  u16* w1t   = (u16*)(ws + 8388608ull);             // 64 MB  tiled [E][F/64][H/64][64][64]
  u16* w2t   = (u16*)(ws + 75497472ull);            // 64 MB  tiled [E][H/64][F/64][64][64]
  u16* hbuf  = (u16*)(ws + 142606336ull);           // 64 MB  [8192][F] bf16
  // ybuf reuses w1t's 64MB region: w1t is dead after gemm1, ybuf written by gemm2.
  float* ybuf = (float*)(ws + 8388608ull);          // 64 MB  2 slabs of [8192][H] f32
  int*   tki    = (int*)(ws + 209715200ull);
  float* tkw    = (float*)(ws + 209747968ull);
  int*   perm   = (int*)(ws + 209780736ull);
  float* pw     = (float*)(ws + 209813504ull);
  int*   counts = (int*)(ws + 209846272ull);        // counts[8], cursor[8], zsum
  int*   cursor = counts + 8;
  float* zsum   = (float*)(counts + 16);
  int*   islot  = (int*)(ws + 209846400ull);        // 32 KB  [T][2] slot map

  hipMemsetAsync(counts, 0, 128, stream);

  // fused: router (0..255) + W1 strips (256..2303) + W2 strips (2304..4351)
  prep_kernel<<<4352, 256, 0, stream>>>(x, Wr, br, xb, tki, tkw, counts, zsum,
                                        W1, w1t, W2, w2t);
  scatter_kernel<<<T_TOK / 256, 256, 0, stream>>>(tki, tkw, counts, cursor, perm, pw,
                                                  islot, zsum, out + OUT_ELEMS);
  // 8 experts x 32 n-blocks x 16 m-slots (256 rows x 128 cols tiles)
  gemm1_kernel<<<4096, 256, 0, stream>>>(xb, w1t, b1, perm, counts, hbuf);
  // 8 experts x 8 n-blocks x 2 K-splits x 16 m-slots
  gemm2_kernel<<<2048, 256, 0, stream>>>(hbuf, w2t, b2, pw, counts, ybuf);
  combine_kernel<<<T_TOK, 256, 0, stream>>>(ybuf, islot, out);
}